// Round 1
// baseline (312.860 us; speedup 1.0000x reference)
//
#include <hip/hip_runtime.h>

typedef __attribute__((ext_vector_type(4))) float f32x4;
typedef __attribute__((ext_vector_type(8))) float f32x8;
typedef __attribute__((ext_vector_type(8))) short bf16x8;

#define S_LEN 4096

__device__ inline short f2bf(float f) {
    union { float f; unsigned u; } v; v.f = f;
    unsigned r = (v.u + 0x7fffu + ((v.u >> 16) & 1u)) >> 16;
    return (short)r;
}

// Wt[g][k], g = m*64 + c (m: 0=Q,1=K,2=V), from W_m[k][c] (fp32 [1024][64])
__global__ __launch_bounds__(256) void wconv_kernel(const float* __restrict__ Wq,
        const float* __restrict__ Wk, const float* __restrict__ Wv,
        short* __restrict__ Wt) {
    int idx = blockIdx.x * 256 + threadIdx.x;          // 3*64*1024 = 196608 total
    int m = idx >> 16, c = (idx >> 10) & 63, k = idx & 1023;
    const float* W = (m == 0) ? Wq : (m == 1) ? Wk : Wv;
    Wt[idx] = f2bf(W[k * 64 + c]);
}

// Each wave: 16 rows x 192 cols, K=1024. Writes Q,K row-major bf16; V transposed.
__global__ __launch_bounds__(256) void qkv_kernel(const float* __restrict__ x,
        const short* __restrict__ Wt, short* __restrict__ Qb,
        short* __restrict__ Kb, short* __restrict__ Vt) {
    const int wv = threadIdx.x >> 6, lane = threadIdx.x & 63;
    const int lr = lane & 15, lg = lane >> 4;
    const int rowbase = blockIdx.x * 64 + wv * 16;

    f32x4 acc[12];
#pragma unroll
    for (int i = 0; i < 12; i++) acc[i] = {0.f, 0.f, 0.f, 0.f};

    const float* xrow = x + (size_t)(rowbase + lr) * 1024;
    for (int k0 = 0; k0 < 1024; k0 += 32) {
        f32x8 xf = *(const f32x8*)(xrow + k0 + lg * 8);
        bf16x8 a;
#pragma unroll
        for (int j = 0; j < 8; j++) a[j] = f2bf(xf[j]);
#pragma unroll
        for (int cf = 0; cf < 12; cf++) {
            bf16x8 b = *(const bf16x8*)(Wt + (size_t)(cf * 16 + lr) * 1024 + k0 + lg * 8);
            acc[cf] = __builtin_amdgcn_mfma_f32_16x16x32_bf16(a, b, acc[cf], 0, 0, 0);
        }
    }

#pragma unroll
    for (int cf = 0; cf < 12; cf++) {
        int g = cf * 16 + lr;       // global output col 0..191 (B-frag col = lane&15)
        int m = g >> 6, cm = g & 63;
#pragma unroll
        for (int r = 0; r < 4; r++) {
            int row = rowbase + lg * 4 + r;   // C row = (lane>>4)*4 + reg
            short bv = f2bf(acc[cf][r]);
            if (m == 0)      Qb[(size_t)row * 64 + cm] = bv;
            else if (m == 1) Kb[(size_t)row * 64 + cm] = bv;
            else {
                int b = row >> 12, s = row & 4095;
                Vt[(size_t)(b * 64 + cm) * S_LEN + s] = bv;
            }
        }
    }
}

// 1 wave per block; 32 q-rows per wave; KV-block = 64; online softmax.
__global__ __launch_bounds__(64) void attn_kernel(const short* __restrict__ Qb,
        const short* __restrict__ Kb, const short* __restrict__ Vt,
        float* __restrict__ out) {
    __shared__ __align__(16) char Plds[32 * 64 * 2];   // P tile, XOR-swizzled
    const int lane = threadIdx.x;
    const int lr = lane & 15, lg = lane >> 4;
    const int qi = blockIdx.x & 127;
    const int bb = blockIdx.x >> 7;
    const int qb = qi * 32;

    bf16x8 qa[2][2];
#pragma unroll
    for (int qf = 0; qf < 2; qf++)
#pragma unroll
        for (int dk = 0; dk < 2; dk++)
            qa[qf][dk] = *(const bf16x8*)(Qb + (size_t)(bb * S_LEN + qb + qf * 16 + lr) * 64 + dk * 32 + lg * 8);

    f32x4 o[2][4];
    float mrun[2][4], lrun[2][4];
#pragma unroll
    for (int qf = 0; qf < 2; qf++) {
#pragma unroll
        for (int df = 0; df < 4; df++) o[qf][df] = {0.f, 0.f, 0.f, 0.f};
#pragma unroll
        for (int r = 0; r < 4; r++) { mrun[qf][r] = -1e30f; lrun[qf][r] = 0.f; }
    }

    const int nkv = (qb + 95) >> 6;   // kv blocks covering cols 0..qb+31
    for (int kvb = 0; kvb < nkv; kvb++) {
        const int kv0 = kvb << 6;

        bf16x8 kb[4][2];
#pragma unroll
        for (int kf = 0; kf < 4; kf++)
#pragma unroll
            for (int dk = 0; dk < 2; dk++)
                kb[kf][dk] = *(const bf16x8*)(Kb + (size_t)(bb * S_LEN + kv0 + kf * 16 + lr) * 64 + dk * 32 + lg * 8);

        f32x4 s[2][4];
#pragma unroll
        for (int qf = 0; qf < 2; qf++)
#pragma unroll
            for (int kf = 0; kf < 4; kf++) {
                f32x4 z = {0.f, 0.f, 0.f, 0.f};
                z = __builtin_amdgcn_mfma_f32_16x16x32_bf16(qa[qf][0], kb[kf][0], z, 0, 0, 0);
                s[qf][kf] = __builtin_amdgcn_mfma_f32_16x16x32_bf16(qa[qf][1], kb[kf][1], z, 0, 0, 0);
            }

        const bool needmask = (kv0 + 63) > qb;
#pragma unroll
        for (int qf = 0; qf < 2; qf++)
#pragma unroll
            for (int kf = 0; kf < 4; kf++)
#pragma unroll
                for (int r = 0; r < 4; r++) {
                    float v = s[qf][kf][r] * 0.125f;     // 1/sqrt(64)
                    if (needmask) {
                        int row = qb + qf * 16 + lg * 4 + r;
                        int col = kv0 + kf * 16 + lr;
                        if (col > row) v = -1e30f;
                    }
                    s[qf][kf][r] = v;
                }

        // online softmax per q-row: row lives on 16 lanes (same lane>>4 group)
#pragma unroll
        for (int qf = 0; qf < 2; qf++)
#pragma unroll
            for (int r = 0; r < 4; r++) {
                float pm = fmaxf(fmaxf(s[qf][0][r], s[qf][1][r]),
                                 fmaxf(s[qf][2][r], s[qf][3][r]));
                pm = fmaxf(pm, __shfl_xor(pm, 1, 64));
                pm = fmaxf(pm, __shfl_xor(pm, 2, 64));
                pm = fmaxf(pm, __shfl_xor(pm, 4, 64));
                pm = fmaxf(pm, __shfl_xor(pm, 8, 64));
                float mnew = fmaxf(mrun[qf][r], pm);
                float fac = __expf(mrun[qf][r] - mnew);
                mrun[qf][r] = mnew;
                lrun[qf][r] *= fac;
#pragma unroll
                for (int df = 0; df < 4; df++) o[qf][df][r] *= fac;

                float rs = 0.f;
#pragma unroll
                for (int kf = 0; kf < 4; kf++) {
                    float p = __expf(s[qf][kf][r] - mnew);
                    rs += p;
                    int ql = qf * 16 + lg * 4 + r;
                    int cl = kf * 16 + lr;
                    int byt = ql * 128 + cl * 2;
                    byt ^= (ql & 7) << 4;                // G4 swizzle
                    *(short*)(Plds + byt) = f2bf(p);
                }
                rs += __shfl_xor(rs, 1, 64);
                rs += __shfl_xor(rs, 2, 64);
                rs += __shfl_xor(rs, 4, 64);
                rs += __shfl_xor(rs, 8, 64);
                lrun[qf][r] += rs;
            }

        // P A-frags from LDS (same swizzle; 16B chunks stay contiguous)
        bf16x8 pa[2][2], vb[2][4];
#pragma unroll
        for (int qf = 0; qf < 2; qf++)
#pragma unroll
            for (int kk = 0; kk < 2; kk++) {
                int ql = qf * 16 + lr;
                int byt = ql * 128 + kk * 64 + lg * 16;
                byt ^= (ql & 7) << 4;
                pa[qf][kk] = *(const bf16x8*)(Plds + byt);
            }
#pragma unroll
        for (int kk = 0; kk < 2; kk++)
#pragma unroll
            for (int df = 0; df < 4; df++)
                vb[kk][df] = *(const bf16x8*)(Vt + (size_t)(bb * 64 + df * 16 + lr) * S_LEN + kv0 + kk * 32 + lg * 8);

#pragma unroll
        for (int qf = 0; qf < 2; qf++)
#pragma unroll
            for (int df = 0; df < 4; df++) {
                o[qf][df] = __builtin_amdgcn_mfma_f32_16x16x32_bf16(pa[qf][0], vb[0][df], o[qf][df], 0, 0, 0);
                o[qf][df] = __builtin_amdgcn_mfma_f32_16x16x32_bf16(pa[qf][1], vb[1][df], o[qf][df], 0, 0, 0);
            }
    }

#pragma unroll
    for (int qf = 0; qf < 2; qf++)
#pragma unroll
        for (int df = 0; df < 4; df++)
#pragma unroll
            for (int r = 0; r < 4; r++) {
                size_t idx = (size_t)(bb * S_LEN + qb + qf * 16 + lg * 4 + r) * 64 + df * 16 + lr;
                out[idx] = o[qf][df][r] / lrun[qf][r];
            }
}

extern "C" void kernel_launch(void* const* d_in, const int* in_sizes, int n_in,
                              void* d_out, int out_size, void* d_ws, size_t ws_size,
                              hipStream_t stream) {
    const float* x  = (const float*)d_in[0];
    const float* Wq = (const float*)d_in[1];
    const float* Wk = (const float*)d_in[2];
    const float* Wv = (const float*)d_in[3];
    float* out = (float*)d_out;

    char* ws = (char*)d_ws;
    short* Wt = (short*)(ws);                 // 192*1024*2  = 384 KB
    short* Qb = (short*)(ws + 0x60000);       // 16384*64*2  = 2 MB
    short* Kb = (short*)(ws + 0x260000);      // 2 MB
    short* Vt = (short*)(ws + 0x460000);      // 4*64*4096*2 = 2 MB  (end: 6.4 MB)

    hipLaunchKernelGGL(wconv_kernel, dim3(768), dim3(256), 0, stream, Wq, Wk, Wv, Wt);
    hipLaunchKernelGGL(qkv_kernel,  dim3(256), dim3(256), 0, stream, x, Wt, Qb, Kb, Vt);
    hipLaunchKernelGGL(attn_kernel, dim3(512), dim3(64),  0, stream, Qb, Kb, Vt, out);
}

// Round 2
// 208.338 us; speedup vs baseline: 1.5017x; 1.5017x over previous
//
#include <hip/hip_runtime.h>

typedef __attribute__((ext_vector_type(4))) float f32x4;
typedef __attribute__((ext_vector_type(8))) float f32x8;
typedef __attribute__((ext_vector_type(8))) short bf16x8;

#define S_LEN 4096

__device__ inline short f2bf(float f) {
    union { float f; unsigned u; } v; v.f = f;
    unsigned r = (v.u + 0x7fffu + ((v.u >> 16) & 1u)) >> 16;
    return (short)r;
}

// Wt[g][k], g = m*64 + c (m: 0=Q,1=K,2=V), from W_m[k][c] (fp32 [1024][64])
__global__ __launch_bounds__(256) void wconv_kernel(const float* __restrict__ Wq,
        const float* __restrict__ Wk, const float* __restrict__ Wv,
        short* __restrict__ Wt) {
    int idx = blockIdx.x * 256 + threadIdx.x;          // 3*64*1024 = 196608 total
    int m = idx >> 16, c = (idx >> 10) & 63, k = idx & 1023;
    const float* W = (m == 0) ? Wq : (m == 1) ? Wk : Wv;
    Wt[idx] = f2bf(W[k * 64 + c]);
}

// Each wave: 16 rows x 192 cols, K=1024. Writes Q,K row-major bf16; V transposed.
__global__ __launch_bounds__(256) void qkv_kernel(const float* __restrict__ x,
        const short* __restrict__ Wt, short* __restrict__ Qb,
        short* __restrict__ Kb, short* __restrict__ Vt) {
    const int wv = threadIdx.x >> 6, lane = threadIdx.x & 63;
    const int lr = lane & 15, lg = lane >> 4;
    const int rowbase = blockIdx.x * 64 + wv * 16;

    f32x4 acc[12];
#pragma unroll
    for (int i = 0; i < 12; i++) acc[i] = {0.f, 0.f, 0.f, 0.f};

    const float* xrow = x + (size_t)(rowbase + lr) * 1024;
    for (int k0 = 0; k0 < 1024; k0 += 32) {
        f32x8 xf = *(const f32x8*)(xrow + k0 + lg * 8);
        bf16x8 a;
#pragma unroll
        for (int j = 0; j < 8; j++) a[j] = f2bf(xf[j]);
#pragma unroll
        for (int cf = 0; cf < 12; cf++) {
            bf16x8 b = *(const bf16x8*)(Wt + (size_t)(cf * 16 + lr) * 1024 + k0 + lg * 8);
            acc[cf] = __builtin_amdgcn_mfma_f32_16x16x32_bf16(a, b, acc[cf], 0, 0, 0);
        }
    }

#pragma unroll
    for (int cf = 0; cf < 12; cf++) {
        int g = cf * 16 + lr;       // global output col 0..191 (B-frag col = lane&15)
        int m = g >> 6, cm = g & 63;
#pragma unroll
        for (int r = 0; r < 4; r++) {
            int row = rowbase + lg * 4 + r;   // C row = (lane>>4)*4 + reg
            short bv = f2bf(acc[cf][r]);
            if (m == 0)      Qb[(size_t)row * 64 + cm] = bv;
            else if (m == 1) Kb[(size_t)row * 64 + cm] = bv;
            else {
                int b = row >> 12, s = row & 4095;
                Vt[(size_t)(b * 64 + cm) * S_LEN + s] = bv;
            }
        }
    }
}

// Decode job -> (qi, chunk).  Per batch: qi<32:1 chunk, <64:2, <96:3, <128:4 -> 320 jobs.
__device__ inline void job_decode(int jb, int& qi, int& c) {
    if (jb < 32)       { qi = jb;               c = 0; }
    else if (jb < 96)  { int u = jb - 32;  qi = 32 + (u >> 1); c = u & 1; }
    else if (jb < 192) { int u = jb - 96;  int q3 = u / 3; qi = 64 + q3; c = u - 3 * q3; }
    else               { int u = jb - 192; qi = 96 + (u >> 2); c = u & 3; }
}
__device__ inline int chunk_base(int qi) {
    if (qi < 32) return qi;
    if (qi < 64) return 32 + 2 * (qi - 32);
    if (qi < 96) return 96 + 3 * (qi - 64);
    return 192 + 4 * (qi - 96);
}

// 1 wave per block; job = (batch, 32-row q-tile, <=1024-key KV chunk).
// Writes un-normalized partial o + per-row m,l.
__global__ __launch_bounds__(64) void attn_partial_kernel(const short* __restrict__ Qb,
        const short* __restrict__ Kb, const short* __restrict__ Vt,
        float* __restrict__ o_part, float* __restrict__ m_part, float* __restrict__ l_part) {
    __shared__ __align__(16) char Plds[32 * 64 * 2];   // P tile, XOR-swizzled
    const int lane = threadIdx.x;
    const int lr = lane & 15, lg = lane >> 4;
    const int j = blockIdx.x;                  // 0..1279
    const int bb = j / 320, jb = j - bb * 320;
    int qi, cch; job_decode(jb, qi, cch);
    const int qb = qi * 32;
    const int kv_start = cch << 10;
    const int kv_end   = min(qb + 32, kv_start + 1024);

    bf16x8 qa[2][2];
#pragma unroll
    for (int qf = 0; qf < 2; qf++)
#pragma unroll
        for (int dk = 0; dk < 2; dk++)
            qa[qf][dk] = *(const bf16x8*)(Qb + (size_t)(bb * S_LEN + qb + qf * 16 + lr) * 64 + dk * 32 + lg * 8);

    f32x4 o[2][4];
    float mrun[2][4], lrun[2][4];
#pragma unroll
    for (int qf = 0; qf < 2; qf++) {
#pragma unroll
        for (int df = 0; df < 4; df++) o[qf][df] = {0.f, 0.f, 0.f, 0.f};
#pragma unroll
        for (int r = 0; r < 4; r++) { mrun[qf][r] = -1e30f; lrun[qf][r] = 0.f; }
    }

    const int kvb0 = kv_start >> 6, kvb1 = (kv_end + 63) >> 6;
    for (int kvb = kvb0; kvb < kvb1; kvb++) {
        const int kv0 = kvb << 6;

        bf16x8 kb[4][2], vb[2][4];
#pragma unroll
        for (int kf = 0; kf < 4; kf++)
#pragma unroll
            for (int dk = 0; dk < 2; dk++)
                kb[kf][dk] = *(const bf16x8*)(Kb + (size_t)(bb * S_LEN + kv0 + kf * 16 + lr) * 64 + dk * 32 + lg * 8);
#pragma unroll
        for (int kk = 0; kk < 2; kk++)
#pragma unroll
            for (int df = 0; df < 4; df++)
                vb[kk][df] = *(const bf16x8*)(Vt + (size_t)(bb * 64 + df * 16 + lr) * S_LEN + kv0 + kk * 32 + lg * 8);

        f32x4 s[2][4];
#pragma unroll
        for (int qf = 0; qf < 2; qf++)
#pragma unroll
            for (int kf = 0; kf < 4; kf++) {
                f32x4 z = {0.f, 0.f, 0.f, 0.f};
                z = __builtin_amdgcn_mfma_f32_16x16x32_bf16(qa[qf][0], kb[kf][0], z, 0, 0, 0);
                s[qf][kf] = __builtin_amdgcn_mfma_f32_16x16x32_bf16(qa[qf][1], kb[kf][1], z, 0, 0, 0);
            }

        const bool needmask = (kv0 + 63) > qb;
#pragma unroll
        for (int qf = 0; qf < 2; qf++)
#pragma unroll
            for (int kf = 0; kf < 4; kf++)
#pragma unroll
                for (int r = 0; r < 4; r++) {
                    float v = s[qf][kf][r] * 0.125f;     // 1/sqrt(64)
                    if (needmask) {
                        int row = qb + qf * 16 + lg * 4 + r;
                        int col = kv0 + kf * 16 + lr;
                        if (col > row) v = -1e30f;
                    }
                    s[qf][kf][r] = v;
                }

        // online softmax per q-row (row lives on the 16 lanes sharing lane>>4)
#pragma unroll
        for (int qf = 0; qf < 2; qf++)
#pragma unroll
            for (int r = 0; r < 4; r++) {
                float pm = fmaxf(fmaxf(s[qf][0][r], s[qf][1][r]),
                                 fmaxf(s[qf][2][r], s[qf][3][r]));
                pm = fmaxf(pm, __shfl_xor(pm, 1, 64));
                pm = fmaxf(pm, __shfl_xor(pm, 2, 64));
                pm = fmaxf(pm, __shfl_xor(pm, 4, 64));
                pm = fmaxf(pm, __shfl_xor(pm, 8, 64));
                float mnew = fmaxf(mrun[qf][r], pm);
                float fac = __expf(mrun[qf][r] - mnew);
                mrun[qf][r] = mnew;
                lrun[qf][r] *= fac;
#pragma unroll
                for (int df = 0; df < 4; df++) o[qf][df][r] *= fac;

                float rs = 0.f;
#pragma unroll
                for (int kf = 0; kf < 4; kf++) {
                    float p = __expf(s[qf][kf][r] - mnew);
                    rs += p;
                    int ql = qf * 16 + lg * 4 + r;
                    int cl = kf * 16 + lr;
                    int byt = ql * 128 + cl * 2;
                    byt ^= (ql & 7) << 4;                // G4 swizzle
                    *(short*)(Plds + byt) = f2bf(p);
                }
                rs += __shfl_xor(rs, 1, 64);
                rs += __shfl_xor(rs, 2, 64);
                rs += __shfl_xor(rs, 4, 64);
                rs += __shfl_xor(rs, 8, 64);
                lrun[qf][r] += rs;
            }

        // P A-frags from LDS (same swizzle; 16B chunks stay contiguous)
        bf16x8 pa[2][2];
#pragma unroll
        for (int qf = 0; qf < 2; qf++)
#pragma unroll
            for (int kk = 0; kk < 2; kk++) {
                int ql = qf * 16 + lr;
                int byt = ql * 128 + kk * 64 + lg * 16;
                byt ^= (ql & 7) << 4;
                pa[qf][kk] = *(const bf16x8*)(Plds + byt);
            }

#pragma unroll
        for (int qf = 0; qf < 2; qf++)
#pragma unroll
            for (int df = 0; df < 4; df++) {
                o[qf][df] = __builtin_amdgcn_mfma_f32_16x16x32_bf16(pa[qf][0], vb[0][df], o[qf][df], 0, 0, 0);
                o[qf][df] = __builtin_amdgcn_mfma_f32_16x16x32_bf16(pa[qf][1], vb[1][df], o[qf][df], 0, 0, 0);
            }
    }

    // write partials
#pragma unroll
    for (int qf = 0; qf < 2; qf++)
#pragma unroll
        for (int df = 0; df < 4; df++)
#pragma unroll
            for (int r = 0; r < 4; r++) {
                int row = qf * 16 + lg * 4 + r;
                o_part[((size_t)j * 32 + row) * 64 + df * 16 + lr] = o[qf][df][r];
            }
    if (lr == 0) {
#pragma unroll
        for (int qf = 0; qf < 2; qf++)
#pragma unroll
            for (int r = 0; r < 4; r++) {
                int row = qf * 16 + lg * 4 + r;
                m_part[(size_t)j * 32 + row] = mrun[qf][r];
                l_part[(size_t)j * 32 + row] = lrun[qf][r];
            }
    }
}

// One block per q-tile: merge <=4 chunk partials, normalize, write fp32 out.
__global__ __launch_bounds__(64) void combine_kernel(const float* __restrict__ o_part,
        const float* __restrict__ m_part, const float* __restrict__ l_part,
        float* __restrict__ out) {
    const int t = blockIdx.x;             // 0..511
    const int bb = t >> 7, qi = t & 127;
    const int qb = qi * 32;
    const int n = (qi >> 5) + 1;
    const int jb0 = bb * 320 + chunk_base(qi);
    const int lane = threadIdx.x;         // = output col

    for (int r = 0; r < 32; r++) {
        float M = -1e30f;
        for (int c = 0; c < n; c++) M = fmaxf(M, m_part[(size_t)(jb0 + c) * 32 + r]);
        float L = 0.f, acc = 0.f;
        for (int c = 0; c < n; c++) {
            float w = __expf(m_part[(size_t)(jb0 + c) * 32 + r] - M);
            L += l_part[(size_t)(jb0 + c) * 32 + r] * w;
            acc += o_part[((size_t)(jb0 + c) * 32 + r) * 64 + lane] * w;
        }
        out[((size_t)(bb * S_LEN + qb + r)) * 64 + lane] = acc / L;
    }
}

extern "C" void kernel_launch(void* const* d_in, const int* in_sizes, int n_in,
                              void* d_out, int out_size, void* d_ws, size_t ws_size,
                              hipStream_t stream) {
    const float* x  = (const float*)d_in[0];
    const float* Wq = (const float*)d_in[1];
    const float* Wk = (const float*)d_in[2];
    const float* Wv = (const float*)d_in[3];
    float* out = (float*)d_out;

    char* ws = (char*)d_ws;
    short* Wt = (short*)(ws);                   // 192*1024*2  = 384 KB
    short* Qb = (short*)(ws + 0x60000);         // 16384*64*2  = 2 MB
    short* Kb = (short*)(ws + 0x260000);        // 2 MB
    short* Vt = (short*)(ws + 0x460000);        // 2 MB
    float* o_part = (float*)(ws + 0x660000);    // 1280*32*64*4 = 10 MB
    float* m_part = (float*)(ws + 0x1060000);   // 160 KB
    float* l_part = (float*)(ws + 0x1088000);   // 160 KB  (end ~17.4 MB)

    hipLaunchKernelGGL(wconv_kernel, dim3(768), dim3(256), 0, stream, Wq, Wk, Wv, Wt);
    hipLaunchKernelGGL(qkv_kernel,  dim3(256), dim3(256), 0, stream, x, Wt, Qb, Kb, Vt);
    hipLaunchKernelGGL(attn_partial_kernel, dim3(1280), dim3(64), 0, stream,
                       Qb, Kb, Vt, o_part, m_part, l_part);
    hipLaunchKernelGGL(combine_kernel, dim3(512), dim3(64), 0, stream,
                       o_part, m_part, l_part, out);
}

// Round 3
// 193.165 us; speedup vs baseline: 1.6197x; 1.0785x over previous
//
#include <hip/hip_runtime.h>

typedef __attribute__((ext_vector_type(4))) float f32x4;
typedef __attribute__((ext_vector_type(8))) short bf16x8;

#define S_LEN 4096

__device__ inline short f2bf(float f) {
    union { float f; unsigned u; } v; v.f = f;
    unsigned r = (v.u + 0x7fffu + ((v.u >> 16) & 1u)) >> 16;
    return (short)r;
}
__device__ inline unsigned pack2bf(float a, float b) {
    return (unsigned)(unsigned short)f2bf(a) | ((unsigned)(unsigned short)f2bf(b) << 16);
}
__device__ inline void gload_lds16(const void* g, void* l) {
    __builtin_amdgcn_global_load_lds(
        (const __attribute__((address_space(1))) unsigned int*)g,
        (__attribute__((address_space(3))) unsigned int*)l, 16, 0, 0);
}

// Wt[g][k], g = m*64 + c (m: 0=Q,1=K,2=V), from W_m[k][c] (fp32 [1024][64])
__global__ __launch_bounds__(256) void wconv_kernel(const float* __restrict__ Wq,
        const float* __restrict__ Wk, const float* __restrict__ Wv,
        short* __restrict__ Wt) {
    int idx = blockIdx.x * 256 + threadIdx.x;
    int m = idx >> 16, c = (idx >> 10) & 63, k = idx & 1023;
    const float* W = (m == 0) ? Wq : (m == 1) ? Wk : Wv;
    Wt[idx] = f2bf(W[k * 64 + c]);
}

// Block: 256 thr = 4 waves, 16 rows, wave w -> cols [w*48, w*48+48). Grid 1024.
// x tile [16][64] f32 staged to LDS via global_load_lds, double-buffered, XOR-swizzled.
__global__ __launch_bounds__(256) void qkv_kernel(const float* __restrict__ x,
        const short* __restrict__ Wt, short* __restrict__ Qb,
        short* __restrict__ Kb, short* __restrict__ Vt) {
    __shared__ __align__(16) float xbuf[2][16 * 64];   // 8 KB
    const int tid = threadIdx.x;
    const int wv = tid >> 6, lane = tid & 63;
    const int lr = lane & 15, lg = lane >> 4;
    const int rowbase = blockIdx.x * 16;

    f32x4 acc[3];
#pragma unroll
    for (int i = 0; i < 3; i++) acc[i] = {0.f, 0.f, 0.f, 0.f};

    // stage tile 0: 256 lanes x 16B = 4 KB. LDS chunk cL of row gets global chunk
    // (cL&8) | ((cL&7) ^ (row&7))  -- involution, matched by the read below.
    {
        int row = tid >> 4, cL = tid & 15;
        int cG = (cL & 8) | ((cL & 7) ^ (row & 7));
        gload_lds16(x + (size_t)(rowbase + row) * 1024 + cG * 4,
                    (char*)xbuf[0] + tid * 16);
    }
    __syncthreads();

    for (int t = 0; t < 16; t++) {
        const int cur = t & 1;
        if (t + 1 < 16) {
            int row = tid >> 4, cL = tid & 15;
            int cG = (cL & 8) | ((cL & 7) ^ (row & 7));
            gload_lds16(x + (size_t)(rowbase + row) * 1024 + (t + 1) * 64 + cG * 4,
                        (char*)xbuf[cur ^ 1] + tid * 16);
        }
        const char* xb = (const char*)xbuf[cur];
        const int k0 = t * 64;
#pragma unroll
        for (int h = 0; h < 2; h++) {
            int s = lr & 7;
            f32x4 a0 = *(const f32x4*)(xb + lr * 256 + (((h * 8) | ((lg * 2) ^ s)) << 4));
            f32x4 a1 = *(const f32x4*)(xb + lr * 256 + (((h * 8) | ((lg * 2 + 1) ^ s)) << 4));
            bf16x8 a;
#pragma unroll
            for (int jj = 0; jj < 4; jj++) { a[jj] = f2bf(a0[jj]); a[4 + jj] = f2bf(a1[jj]); }
#pragma unroll
            for (int cf = 0; cf < 3; cf++) {
                bf16x8 b = *(const bf16x8*)(Wt + (size_t)((wv * 3 + cf) * 16 + lr) * 1024
                                            + k0 + h * 32 + lg * 8);
                acc[cf] = __builtin_amdgcn_mfma_f32_16x16x32_bf16(a, b, acc[cf], 0, 0, 0);
            }
        }
        __syncthreads();
    }

#pragma unroll
    for (int cf = 0; cf < 3; cf++) {
        int gcol = wv * 48 + cf * 16 + lr;
        int m = gcol >> 6, cm = gcol & 63;
#pragma unroll
        for (int r = 0; r < 4; r++) {
            int row = rowbase + lg * 4 + r;
            short bv = f2bf(acc[cf][r]);
            if (m == 0)      Qb[(size_t)row * 64 + cm] = bv;
            else if (m == 1) Kb[(size_t)row * 64 + cm] = bv;
            else {
                int b = row >> 12, ss = row & 4095;
                Vt[(size_t)(b * 64 + cm) * S_LEN + ss] = bv;
            }
        }
    }
}

// 1 wave/block. Swapped-operand attention: S^T = mfma(K,Q) puts each q-row's
// scores along the lane's regs+lg; O^T = mfma(Vt, P).
__global__ __launch_bounds__(64) void attn_partial_kernel(const short* __restrict__ Qb,
        const short* __restrict__ Kb, const short* __restrict__ Vt,
        float* __restrict__ o_part, float* __restrict__ m_part, float* __restrict__ l_part,
        int G, int NPB, int C) {
    __shared__ __align__(16) char Plds[32 * 64 * 2];
    const int lane = threadIdx.x;
    const int lr = lane & 15, lg = lane >> 4;
    const int j = blockIdx.x;
    const int bb = j / NPB;
    int jb = j - bb * NPB;
    int g = 0, base = 0;
    while (jb >= base + G * (g + 1)) { base += G * (g + 1); g++; }
    int u = jb - base;
    int qdiv = u / (g + 1);
    const int qi = g * G + qdiv;
    const int cch = u - qdiv * (g + 1);
    const int qb = qi * 32;
    const int kv_start = cch * C;
    const int kv_end = min(qb + 32, kv_start + C);

    bf16x8 qa[2][2];
#pragma unroll
    for (int qf = 0; qf < 2; qf++)
#pragma unroll
        for (int dk = 0; dk < 2; dk++)
            qa[qf][dk] = *(const bf16x8*)(Qb + (size_t)(bb * S_LEN + qb + qf * 16 + lr) * 64 + dk * 32 + lg * 8);

    f32x4 o[2][4];                       // o[qf][df]: O^T frag, d=df*16+lg*4+r, q=qf*16+lr
    float mrun[2] = {-1e30f, -1e30f}, lrun[2] = {0.f, 0.f};
#pragma unroll
    for (int qf = 0; qf < 2; qf++)
#pragma unroll
        for (int df = 0; df < 4; df++) o[qf][df] = {0.f, 0.f, 0.f, 0.f};

    const int kvb0 = kv_start >> 6, kvb1 = (kv_end + 63) >> 6;
    for (int kvb = kvb0; kvb < kvb1; kvb++) {
        const int kv0 = kvb << 6;

        bf16x8 kb[4][2], vb[2][4];
#pragma unroll
        for (int kf = 0; kf < 4; kf++)
#pragma unroll
            for (int dk = 0; dk < 2; dk++)
                kb[kf][dk] = *(const bf16x8*)(Kb + (size_t)(bb * S_LEN + kv0 + kf * 16 + lr) * 64 + dk * 32 + lg * 8);
#pragma unroll
        for (int kk = 0; kk < 2; kk++)
#pragma unroll
            for (int df = 0; df < 4; df++)
                vb[kk][df] = *(const bf16x8*)(Vt + (size_t)(bb * 64 + df * 16 + lr) * S_LEN + kv0 + kk * 32 + lg * 8);

        // S^T: s[qf][kf][r] = score(q = qb+qf*16+lr, k = kv0+kf*16+lg*4+r)
        f32x4 s[2][4];
#pragma unroll
        for (int qf = 0; qf < 2; qf++)
#pragma unroll
            for (int kf = 0; kf < 4; kf++) {
                f32x4 z = {0.f, 0.f, 0.f, 0.f};
                z = __builtin_amdgcn_mfma_f32_16x16x32_bf16(kb[kf][0], qa[qf][0], z, 0, 0, 0);
                s[qf][kf] = __builtin_amdgcn_mfma_f32_16x16x32_bf16(kb[kf][1], qa[qf][1], z, 0, 0, 0);
            }

        const bool needmask = (kv0 + 63) > qb;
#pragma unroll
        for (int qf = 0; qf < 2; qf++)
#pragma unroll
            for (int kf = 0; kf < 4; kf++)
#pragma unroll
                for (int r = 0; r < 4; r++) {
                    float v = s[qf][kf][r] * 0.125f;
                    if (needmask) {
                        int row = qb + qf * 16 + lr;
                        int col = kv0 + kf * 16 + lg * 4 + r;
                        if (col > row) v = -1e30f;
                    }
                    s[qf][kf][r] = v;
                }

#pragma unroll
        for (int qf = 0; qf < 2; qf++) {
            float pm = -1e30f;
#pragma unroll
            for (int kf = 0; kf < 4; kf++)
#pragma unroll
                for (int r = 0; r < 4; r++) pm = fmaxf(pm, s[qf][kf][r]);
            pm = fmaxf(pm, __shfl_xor(pm, 16, 64));
            pm = fmaxf(pm, __shfl_xor(pm, 32, 64));
            float mnew = fmaxf(mrun[qf], pm);
            float fac = __expf(mrun[qf] - mnew);
            mrun[qf] = mnew;

            const int q = qf * 16 + lr;
            const int swz = (q & 7) << 4;
            float rs = 0.f;
#pragma unroll
            for (int kf = 0; kf < 4; kf++) {
                float p0 = __expf(s[qf][kf][0] - mnew);
                float p1 = __expf(s[qf][kf][1] - mnew);
                float p2 = __expf(s[qf][kf][2] - mnew);
                float p3 = __expf(s[qf][kf][3] - mnew);
                rs += (p0 + p1) + (p2 + p3);
                uint2 w; w.x = pack2bf(p0, p1); w.y = pack2bf(p2, p3);
                int byt = (q * 128 + kf * 32 + lg * 8) ^ swz;
                *(uint2*)(Plds + byt) = w;
            }
            rs += __shfl_xor(rs, 16, 64);
            rs += __shfl_xor(rs, 32, 64);
            lrun[qf] = lrun[qf] * fac + rs;
#pragma unroll
            for (int df = 0; df < 4; df++)
#pragma unroll
                for (int r = 0; r < 4; r++) o[qf][df][r] *= fac;
        }

        // P B-frags: lane needs P[q = qf*16+lr][k = kk*32 + lg*8 .. +7]
        bf16x8 pa[2][2];
#pragma unroll
        for (int qf = 0; qf < 2; qf++)
#pragma unroll
            for (int kk = 0; kk < 2; kk++) {
                int q = qf * 16 + lr;
                int byt = (q * 128 + kk * 64 + lg * 16) ^ ((q & 7) << 4);
                pa[qf][kk] = *(const bf16x8*)(Plds + byt);
            }

#pragma unroll
        for (int qf = 0; qf < 2; qf++)
#pragma unroll
            for (int df = 0; df < 4; df++) {
                o[qf][df] = __builtin_amdgcn_mfma_f32_16x16x32_bf16(vb[0][df], pa[qf][0], o[qf][df], 0, 0, 0);
                o[qf][df] = __builtin_amdgcn_mfma_f32_16x16x32_bf16(vb[1][df], pa[qf][1], o[qf][df], 0, 0, 0);
            }
    }

#pragma unroll
    for (int qf = 0; qf < 2; qf++)
#pragma unroll
        for (int df = 0; df < 4; df++)
            *(f32x4*)(o_part + ((size_t)j * 32 + qf * 16 + lr) * 64 + df * 16 + lg * 4) = o[qf][df];
    if (lg == 0) {
#pragma unroll
        for (int qf = 0; qf < 2; qf++) {
            m_part[(size_t)j * 32 + qf * 16 + lr] = mrun[qf];
            l_part[(size_t)j * 32 + qf * 16 + lr] = lrun[qf];
        }
    }
}

__global__ __launch_bounds__(64) void combine_kernel(const float* __restrict__ o_part,
        const float* __restrict__ m_part, const float* __restrict__ l_part,
        float* __restrict__ out, int G, int NPB) {
    const int t = blockIdx.x;
    const int bb = t >> 7, qi = t & 127;
    const int g = qi / G;
    const int n = g + 1;
    const int jb0 = bb * NPB + G * g * (g + 1) / 2 + (qi % G) * n;
    const int lane = threadIdx.x;

    for (int r = 0; r < 32; r++) {
        float M = -1e30f;
        for (int c = 0; c < n; c++) M = fmaxf(M, m_part[(size_t)(jb0 + c) * 32 + r]);
        float L = 0.f, acc = 0.f;
        for (int c = 0; c < n; c++) {
            float w = __expf(m_part[(size_t)(jb0 + c) * 32 + r] - M);
            L += l_part[(size_t)(jb0 + c) * 32 + r] * w;
            acc += o_part[((size_t)(jb0 + c) * 32 + r) * 64 + lane] * w;
        }
        out[((size_t)(bb * S_LEN + qi * 32 + r)) * 64 + lane] = acc / L;
    }
}

extern "C" void kernel_launch(void* const* d_in, const int* in_sizes, int n_in,
                              void* d_out, int out_size, void* d_ws, size_t ws_size,
                              hipStream_t stream) {
    const float* x  = (const float*)d_in[0];
    const float* Wq = (const float*)d_in[1];
    const float* Wk = (const float*)d_in[2];
    const float* Wv = (const float*)d_in[3];
    float* out = (float*)d_out;

    char* ws = (char*)d_ws;
    short* Wt = (short*)(ws);                   // 384 KB
    short* Qb = (short*)(ws + 0x60000);         // 2 MB
    short* Kb = (short*)(ws + 0x260000);        // 2 MB
    short* Vt = (short*)(ws + 0x460000);        // 2 MB

    // chunking: prefer C=512 (G=16, NPB=576) if workspace allows, else C=1024.
    int G = 16, NPB = 576, C = 512;
    size_t need = 0x660000 + (size_t)4 * NPB * 32 * 66 * 4;
    if (need > ws_size) { G = 32; NPB = 320; C = 1024; }
    const int njobs = 4 * NPB;
    float* o_part = (float*)(ws + 0x660000);
    float* m_part = o_part + (size_t)njobs * 32 * 64;
    float* l_part = m_part + (size_t)njobs * 32;

    hipLaunchKernelGGL(wconv_kernel, dim3(768), dim3(256), 0, stream, Wq, Wk, Wv, Wt);
    hipLaunchKernelGGL(qkv_kernel,  dim3(1024), dim3(256), 0, stream, x, Wt, Qb, Kb, Vt);
    hipLaunchKernelGGL(attn_partial_kernel, dim3(njobs), dim3(64), 0, stream,
                       Qb, Kb, Vt, o_part, m_part, l_part, G, NPB, C);
    hipLaunchKernelGGL(combine_kernel, dim3(512), dim3(64), 0, stream,
                       o_part, m_part, l_part, out, G, NPB);
}

// Round 4
// 118.597 us; speedup vs baseline: 2.6380x; 1.6288x over previous
//
#include <hip/hip_runtime.h>

typedef __attribute__((ext_vector_type(4))) float f32x4;
typedef __attribute__((ext_vector_type(8))) short bf16x8;

#define S_LEN 4096

__device__ inline short f2bf(float f) {
    union { float f; unsigned u; } v; v.f = f;
    unsigned r = (v.u + 0x7fffu + ((v.u >> 16) & 1u)) >> 16;
    return (short)r;
}
__device__ inline unsigned pack2bf(float a, float b) {
    return (unsigned)(unsigned short)f2bf(a) | ((unsigned)(unsigned short)f2bf(b) << 16);
}
__device__ inline void gload_lds16(const void* g, void* l) {
    __builtin_amdgcn_global_load_lds(
        (const __attribute__((address_space(1))) unsigned int*)g,
        (__attribute__((address_space(3))) unsigned int*)l, 16, 0, 0);
}

// Wt[g][k], g = m*64 + c (m: 0=Q,1=K,2=V), from W_m[k][c] (fp32 [1024][64])
__global__ __launch_bounds__(256) void wconv_kernel(const float* __restrict__ Wq,
        const float* __restrict__ Wk, const float* __restrict__ Wv,
        short* __restrict__ Wt) {
    int idx = blockIdx.x * 256 + threadIdx.x;
    int m = idx >> 16, c = (idx >> 10) & 63, k = idx & 1023;
    const float* W = (m == 0) ? Wq : (m == 1) ? Wk : Wv;
    Wt[idx] = f2bf(W[k * 64 + c]);
}

// Block: 256 thr = 4 waves, 16 rows, wave w -> cols [w*48, w*48+48). Grid 1024.
__global__ __launch_bounds__(256) void qkv_kernel(const float* __restrict__ x,
        const short* __restrict__ Wt, short* __restrict__ Qb,
        short* __restrict__ Kb, short* __restrict__ Vt) {
    __shared__ __align__(16) float xbuf[2][16 * 64];   // 8 KB
    const int tid = threadIdx.x;
    const int wv = tid >> 6, lane = tid & 63;
    const int lr = lane & 15, lg = lane >> 4;
    const int rowbase = blockIdx.x * 16;

    f32x4 acc[3];
#pragma unroll
    for (int i = 0; i < 3; i++) acc[i] = {0.f, 0.f, 0.f, 0.f};

    {
        int row = tid >> 4, cL = tid & 15;
        int cG = (cL & 8) | ((cL & 7) ^ (row & 7));
        gload_lds16(x + (size_t)(rowbase + row) * 1024 + cG * 4,
                    (char*)xbuf[0] + tid * 16);
    }
    __syncthreads();

    for (int t = 0; t < 16; t++) {
        const int cur = t & 1;
        if (t + 1 < 16) {
            int row = tid >> 4, cL = tid & 15;
            int cG = (cL & 8) | ((cL & 7) ^ (row & 7));
            gload_lds16(x + (size_t)(rowbase + row) * 1024 + (t + 1) * 64 + cG * 4,
                        (char*)xbuf[cur ^ 1] + tid * 16);
        }
        const char* xb = (const char*)xbuf[cur];
        const int k0 = t * 64;
#pragma unroll
        for (int h = 0; h < 2; h++) {
            int s = lr & 7;
            f32x4 a0 = *(const f32x4*)(xb + lr * 256 + (((h * 8) | ((lg * 2) ^ s)) << 4));
            f32x4 a1 = *(const f32x4*)(xb + lr * 256 + (((h * 8) | ((lg * 2 + 1) ^ s)) << 4));
            bf16x8 a;
#pragma unroll
            for (int jj = 0; jj < 4; jj++) { a[jj] = f2bf(a0[jj]); a[4 + jj] = f2bf(a1[jj]); }
#pragma unroll
            for (int cf = 0; cf < 3; cf++) {
                bf16x8 b = *(const bf16x8*)(Wt + (size_t)((wv * 3 + cf) * 16 + lr) * 1024
                                            + k0 + h * 32 + lg * 8);
                acc[cf] = __builtin_amdgcn_mfma_f32_16x16x32_bf16(a, b, acc[cf], 0, 0, 0);
            }
        }
        __syncthreads();
    }

#pragma unroll
    for (int cf = 0; cf < 3; cf++) {
        int gcol = wv * 48 + cf * 16 + lr;
        int m = gcol >> 6, cm = gcol & 63;
#pragma unroll
        for (int r = 0; r < 4; r++) {
            int row = rowbase + lg * 4 + r;
            short bv = f2bf(acc[cf][r]);
            if (m == 0)      Qb[(size_t)row * 64 + cm] = bv;
            else if (m == 1) Kb[(size_t)row * 64 + cm] = bv;
            else {
                int b = row >> 12, ss = row & 4095;
                Vt[(size_t)(b * 64 + cm) * S_LEN + ss] = bv;
            }
        }
    }
}

// 1 wave/block. Swapped-operand attention: S^T = mfma(K,Q), O^T = mfma(Vt, P).
__global__ __launch_bounds__(64) void attn_partial_kernel(const short* __restrict__ Qb,
        const short* __restrict__ Kb, const short* __restrict__ Vt,
        float* __restrict__ o_part, float* __restrict__ m_part, float* __restrict__ l_part,
        int G, int NPB, int C) {
    __shared__ __align__(16) char Plds[32 * 64 * 2];
    const int lane = threadIdx.x;
    const int lr = lane & 15, lg = lane >> 4;
    const int j = blockIdx.x;
    const int bb = j / NPB;
    int jb = j - bb * NPB;
    int g = 0, base = 0;
    while (jb >= base + G * (g + 1)) { base += G * (g + 1); g++; }
    int u = jb - base;
    int qdiv = u / (g + 1);
    const int qi = g * G + qdiv;
    const int cch = u - qdiv * (g + 1);
    const int qb = qi * 32;
    const int kv_start = cch * C;
    const int kv_end = min(qb + 32, kv_start + C);

    bf16x8 qa[2][2];
#pragma unroll
    for (int qf = 0; qf < 2; qf++)
#pragma unroll
        for (int dk = 0; dk < 2; dk++)
            qa[qf][dk] = *(const bf16x8*)(Qb + (size_t)(bb * S_LEN + qb + qf * 16 + lr) * 64 + dk * 32 + lg * 8);

    f32x4 o[2][4];
    float mrun[2] = {-1e30f, -1e30f}, lrun[2] = {0.f, 0.f};
#pragma unroll
    for (int qf = 0; qf < 2; qf++)
#pragma unroll
        for (int df = 0; df < 4; df++) o[qf][df] = {0.f, 0.f, 0.f, 0.f};

    const int kvb0 = kv_start >> 6, kvb1 = (kv_end + 63) >> 6;
    for (int kvb = kvb0; kvb < kvb1; kvb++) {
        const int kv0 = kvb << 6;

        bf16x8 kb[4][2], vb[2][4];
#pragma unroll
        for (int kf = 0; kf < 4; kf++)
#pragma unroll
            for (int dk = 0; dk < 2; dk++)
                kb[kf][dk] = *(const bf16x8*)(Kb + (size_t)(bb * S_LEN + kv0 + kf * 16 + lr) * 64 + dk * 32 + lg * 8);
#pragma unroll
        for (int kk = 0; kk < 2; kk++)
#pragma unroll
            for (int df = 0; df < 4; df++)
                vb[kk][df] = *(const bf16x8*)(Vt + (size_t)(bb * 64 + df * 16 + lr) * S_LEN + kv0 + kk * 32 + lg * 8);

        f32x4 s[2][4];
#pragma unroll
        for (int qf = 0; qf < 2; qf++)
#pragma unroll
            for (int kf = 0; kf < 4; kf++) {
                f32x4 z = {0.f, 0.f, 0.f, 0.f};
                z = __builtin_amdgcn_mfma_f32_16x16x32_bf16(kb[kf][0], qa[qf][0], z, 0, 0, 0);
                s[qf][kf] = __builtin_amdgcn_mfma_f32_16x16x32_bf16(kb[kf][1], qa[qf][1], z, 0, 0, 0);
            }

        const bool needmask = (kv0 + 63) > qb;
#pragma unroll
        for (int qf = 0; qf < 2; qf++)
#pragma unroll
            for (int kf = 0; kf < 4; kf++)
#pragma unroll
                for (int r = 0; r < 4; r++) {
                    float v = s[qf][kf][r] * 0.125f;
                    if (needmask) {
                        int row = qb + qf * 16 + lr;
                        int col = kv0 + kf * 16 + lg * 4 + r;
                        if (col > row) v = -1e30f;
                    }
                    s[qf][kf][r] = v;
                }

#pragma unroll
        for (int qf = 0; qf < 2; qf++) {
            float pm = -1e30f;
#pragma unroll
            for (int kf = 0; kf < 4; kf++)
#pragma unroll
                for (int r = 0; r < 4; r++) pm = fmaxf(pm, s[qf][kf][r]);
            pm = fmaxf(pm, __shfl_xor(pm, 16, 64));
            pm = fmaxf(pm, __shfl_xor(pm, 32, 64));
            float mnew = fmaxf(mrun[qf], pm);
            float fac = __expf(mrun[qf] - mnew);
            mrun[qf] = mnew;

            const int q = qf * 16 + lr;
            const int swz = (q & 7) << 4;
            float rs = 0.f;
#pragma unroll
            for (int kf = 0; kf < 4; kf++) {
                float p0 = __expf(s[qf][kf][0] - mnew);
                float p1 = __expf(s[qf][kf][1] - mnew);
                float p2 = __expf(s[qf][kf][2] - mnew);
                float p3 = __expf(s[qf][kf][3] - mnew);
                rs += (p0 + p1) + (p2 + p3);
                uint2 w; w.x = pack2bf(p0, p1); w.y = pack2bf(p2, p3);
                int byt = (q * 128 + kf * 32 + lg * 8) ^ swz;
                *(uint2*)(Plds + byt) = w;
            }
            rs += __shfl_xor(rs, 16, 64);
            rs += __shfl_xor(rs, 32, 64);
            lrun[qf] = lrun[qf] * fac + rs;
#pragma unroll
            for (int df = 0; df < 4; df++)
#pragma unroll
                for (int r = 0; r < 4; r++) o[qf][df][r] *= fac;
        }

        bf16x8 pa[2][2];
#pragma unroll
        for (int qf = 0; qf < 2; qf++)
#pragma unroll
            for (int kk = 0; kk < 2; kk++) {
                int q = qf * 16 + lr;
                int byt = (q * 128 + kk * 64 + lg * 16) ^ ((q & 7) << 4);
                pa[qf][kk] = *(const bf16x8*)(Plds + byt);
            }

#pragma unroll
        for (int qf = 0; qf < 2; qf++)
#pragma unroll
            for (int df = 0; df < 4; df++) {
                o[qf][df] = __builtin_amdgcn_mfma_f32_16x16x32_bf16(vb[0][df], pa[qf][0], o[qf][df], 0, 0, 0);
                o[qf][df] = __builtin_amdgcn_mfma_f32_16x16x32_bf16(vb[1][df], pa[qf][1], o[qf][df], 0, 0, 0);
            }
    }

#pragma unroll
    for (int qf = 0; qf < 2; qf++)
#pragma unroll
        for (int df = 0; df < 4; df++)
            *(f32x4*)(o_part + ((size_t)j * 32 + qf * 16 + lr) * 64 + df * 16 + lg * 4) = o[qf][df];
    if (lg == 0) {
#pragma unroll
        for (int qf = 0; qf < 2; qf++) {
            m_part[(size_t)j * 32 + qf * 16 + lr] = mrun[qf];
            l_part[(size_t)j * 32 + qf * 16 + lr] = lrun[qf];
        }
    }
}

// One thread per output element; m/l loads are wave-uniform, o loads coalesced.
__global__ __launch_bounds__(256) void combine_kernel(const float* __restrict__ o_part,
        const float* __restrict__ m_part, const float* __restrict__ l_part,
        float* __restrict__ out, int G, int NPB) {
    const int idx = blockIdx.x * 256 + threadIdx.x;    // 0 .. 4*4096*64-1
    const int col = idx & 63;
    const int rowg = idx >> 6;
    const int bb = rowg >> 12;
    const int srow = rowg & 4095;
    const int qi = srow >> 5;
    const int r = srow & 31;
    const int g = qi / G;
    const int n = g + 1;
    const int jb0 = bb * NPB + G * g * (g + 1) / 2 + (qi - g * G) * n;

    float M = -1e30f;
    for (int c = 0; c < n; c++) M = fmaxf(M, m_part[(size_t)(jb0 + c) * 32 + r]);
    float L = 0.f, acc = 0.f;
    for (int c = 0; c < n; c++) {
        float w = __expf(m_part[(size_t)(jb0 + c) * 32 + r] - M);
        L += l_part[(size_t)(jb0 + c) * 32 + r] * w;
        acc += o_part[((size_t)(jb0 + c) * 32 + r) * 64 + col] * w;
    }
    out[idx] = acc / L;
}

extern "C" void kernel_launch(void* const* d_in, const int* in_sizes, int n_in,
                              void* d_out, int out_size, void* d_ws, size_t ws_size,
                              hipStream_t stream) {
    const float* x  = (const float*)d_in[0];
    const float* Wq = (const float*)d_in[1];
    const float* Wk = (const float*)d_in[2];
    const float* Wv = (const float*)d_in[3];
    float* out = (float*)d_out;

    char* ws = (char*)d_ws;
    short* Wt = (short*)(ws);                   // 384 KB
    short* Qb = (short*)(ws + 0x60000);         // 2 MB
    short* Kb = (short*)(ws + 0x260000);        // 2 MB
    short* Vt = (short*)(ws + 0x460000);        // 2 MB

    // chunk tiers: C=256 (G=8, NPB=1088) -> C=512 -> C=1024, by workspace.
    int G = 8, NPB = 1088, C = 256;
    {
        size_t need = 0x660000 + (size_t)4 * NPB * 32 * 66 * 4;
        if (need > ws_size) { G = 16; NPB = 576; C = 512; }
        need = 0x660000 + (size_t)4 * NPB * 32 * 66 * 4;
        if (need > ws_size) { G = 32; NPB = 320; C = 1024; }
    }
    const int njobs = 4 * NPB;
    float* o_part = (float*)(ws + 0x660000);
    float* m_part = o_part + (size_t)njobs * 32 * 64;
    float* l_part = m_part + (size_t)njobs * 32;

    hipLaunchKernelGGL(wconv_kernel, dim3(768), dim3(256), 0, stream, Wq, Wk, Wv, Wt);
    hipLaunchKernelGGL(qkv_kernel,  dim3(1024), dim3(256), 0, stream, x, Wt, Qb, Kb, Vt);
    hipLaunchKernelGGL(attn_partial_kernel, dim3(njobs), dim3(64), 0, stream,
                       Qb, Kb, Vt, o_part, m_part, l_part, G, NPB, C);
    hipLaunchKernelGGL(combine_kernel, dim3(4096), dim3(256), 0, stream,
                       o_part, m_part, l_part, out, G, NPB);
}